// Round 12
// baseline (240.004 us; speedup 1.0000x reference)
//
#include <hip/hip_runtime.h>

#define EMBED 1024
#define HEADS 16
#define HDIM  64
#define SEQ   2048
#define BATCH 4
#define MTOT  (BATCH*SEQ)

typedef __attribute__((ext_vector_type(8)))  short short8;
typedef __attribute__((ext_vector_type(4)))  float f32x4;
typedef __attribute__((ext_vector_type(16))) float f32x16;

#define GLOAD_LDS16(g, l) \
  __builtin_amdgcn_global_load_lds((const __attribute__((address_space(1))) void*)(g), \
                                   (__attribute__((address_space(3))) void*)(l), 16, 0, 0)

__device__ inline unsigned short f2bf(float f) {
  union { float f; unsigned u; } v; v.f = f;
  unsigned r = v.u + 0x7FFF + ((v.u >> 16) & 1);
  return (unsigned short)(r >> 16);
}

__device__ inline unsigned cvtpk(float lo, float hi) {
  unsigned r;
  asm("v_cvt_pk_bf16_f32 %0, %1, %2" : "=v"(r) : "v"(lo), "v"(hi));
  return r;
}

// raw 2^x — single trans-pipe instr; inputs bounded (|x| < ~8), no edge cases
__device__ inline float vexp2(float x) {
  float r;
  asm("v_exp_f32 %0, %1" : "=v"(r) : "v"(x));
  return r;
}

// v_permlane32_swap_b32 vdst, vsrc — HW semantics (R6/R7 falsification test):
// new vdst[32:63] = old vsrc[0:31]; new vsrc[0:31] = old vdst[32:63].
#define PLSWAP(a, b) asm("v_permlane32_swap_b32 %0, %1" : "+v"(a), "+v"(b))

__device__ inline short8 mk8(unsigned w0, unsigned w1, unsigned w2, unsigned w3) {
  union { unsigned u[4]; short8 s; } x;
  x.u[0] = w0; x.u[1] = w1; x.u[2] = w2; x.u[3] = w3;
  return x.s;
}

// ---------- kernel 1: x fp32 -> bf16 ----------
__global__ void cvt_x(const float* __restrict__ x, unsigned short* __restrict__ xb) {
  int i = (blockIdx.x * blockDim.x + threadIdx.x) * 8;
  f32x4 a = *(const f32x4*)(x + i);
  f32x4 b = *(const f32x4*)(x + i + 4);
  unsigned short o[8];
  o[0]=f2bf(a[0]); o[1]=f2bf(a[1]); o[2]=f2bf(a[2]); o[3]=f2bf(a[3]);
  o[4]=f2bf(b[0]); o[5]=f2bf(b[1]); o[6]=f2bf(b[2]); o[7]=f2bf(b[3]);
  *(short8*)(xb + i) = *(short8*)o;
}

// ---------- kernel 2: W [K][N] fp32 -> Wt [N][K] bf16 (x3) ----------
__global__ void transpose_w(const float* __restrict__ Wq, const float* __restrict__ Wk,
                            const float* __restrict__ Wv, unsigned short* __restrict__ Wtb) {
  __shared__ float tile[32][33];
  int wsel = blockIdx.z;
  const float* W = wsel == 0 ? Wq : (wsel == 1 ? Wk : Wv);
  int k0 = blockIdx.x * 32, n0 = blockIdx.y * 32;
  int tx = threadIdx.x & 31, ty = threadIdx.x >> 5;
  for (int i = 0; i < 4; ++i)
    tile[ty + i*8][tx] = W[(k0 + ty + i*8) * EMBED + n0 + tx];
  __syncthreads();
  unsigned short* o = Wtb + wsel * EMBED * EMBED;
  for (int i = 0; i < 4; ++i)
    o[(n0 + ty + i*8) * EMBED + k0 + tx] = f2bf(tile[tx][ty + i*8]);
}

// ---------- kernel 3: QKV projection GEMM ----------
// Q output is pre-scaled by 0.125*log2(e) so attn's softmax needs no per-score FMA.
__global__ __launch_bounds__(256)
void qkv_gemm(const unsigned short* __restrict__ xb, const unsigned short* __restrict__ Wtb,
              const float* __restrict__ bq, const float* __restrict__ bk, const float* __restrict__ bv,
              unsigned short* __restrict__ Qb, unsigned short* __restrict__ Kb,
              unsigned short* __restrict__ Vt) {
  __shared__ unsigned short As[128 * 72];
  __shared__ unsigned short Bs[128 * 72];
  int wsel = blockIdx.z;
  int m0 = blockIdx.x * 128, n0 = blockIdx.y * 128;
  int t = threadIdx.x, lane = t & 63, wave = t >> 6;
  int wr = wave >> 1, wc = wave & 1;
  int lr = lane & 15, lg = lane >> 4;
  const unsigned short* Wt = Wtb + wsel * (EMBED * EMBED);
  const float* bias = wsel == 0 ? bq : (wsel == 1 ? bk : bv);

  f32x4 acc[4][4] = {};

  for (int kt = 0; kt < EMBED / 64; ++kt) {
    int k0 = kt * 64;
    for (int i = 0; i < 4; ++i) {
      int c = i * 256 + t;
      int row = c >> 3, col8 = c & 7;
      short8 va = *(const short8*)(xb + (m0 + row) * EMBED + k0 + col8 * 8);
      short8 vb = *(const short8*)(Wt + (n0 + row) * EMBED + k0 + col8 * 8);
      *(short8*)(As + row * 72 + col8 * 8) = va;
      *(short8*)(Bs + row * 72 + col8 * 8) = vb;
    }
    __syncthreads();
    for (int kk = 0; kk < 2; ++kk) {
      short8 af[4], bfr[4];
      for (int mf = 0; mf < 4; ++mf)
        af[mf] = *(const short8*)(As + (wr * 64 + mf * 16 + lr) * 72 + kk * 32 + lg * 8);
      for (int nf = 0; nf < 4; ++nf)
        bfr[nf] = *(const short8*)(Bs + (wc * 64 + nf * 16 + lr) * 72 + kk * 32 + lg * 8);
      for (int mf = 0; mf < 4; ++mf)
        for (int nf = 0; nf < 4; ++nf)
          acc[mf][nf] = __builtin_amdgcn_mfma_f32_16x16x32_bf16(af[mf], bfr[nf], acc[mf][nf], 0, 0, 0);
    }
    __syncthreads();
  }

  const float SCLQ = 0.125f * 1.44269504088896340736f;
  for (int nf = 0; nf < 4; ++nf) {
    int n = n0 + wc * 64 + nf * 16 + lr;
    float bval = bias[n];
    int h = n >> 6, d = n & 63;
    for (int mf = 0; mf < 4; ++mf) {
      for (int r = 0; r < 4; ++r) {
        int m = m0 + wr * 64 + mf * 16 + lg * 4 + r;
        int b = m >> 11, s = m & 2047;
        float oval = acc[mf][nf][r] + bval;
        if (wsel == 0) oval *= SCLQ;   // wave-uniform branch
        unsigned short bfv = f2bf(oval);
        if (wsel == 0)      Qb[((b * HEADS + h) * SEQ + s) * HDIM + d] = bfv;
        else if (wsel == 1) Kb[((b * HEADS + h) * SEQ + s) * HDIM + d] = bfv;
        else                Vt[((b * HEADS + h) * HDIM + d) * SEQ + s] = bfv;
      }
    }
  }
}

// ---------- kernel 4: flash attention, 32x32 MFMA, swapped QK^T, 64 q/wave ----------
// Each wave owns 64 q-rows (two 32-q halves sharing each K/V tile read): per-iter
// fixed costs (barrier, stage latency, K ds_reads) amortize 2x, LDS traffic per
// unit work halves. K/V frag reads are CSE-able LDS expressions (allocator picks
// regs vs re-read — avoids forced spills, R10 lesson).
__global__ __launch_bounds__(256)
void attn(const unsigned short* __restrict__ Qb, const unsigned short* __restrict__ Kb,
          const unsigned short* __restrict__ Vt, const float* __restrict__ rel_bias,
          float* __restrict__ out) {
  __shared__ unsigned short KVs[16384];   // K buf0 | K buf1 | V buf0 | V buf1 (4096 ea)
  __shared__ float bias_l[33];
  __shared__ float dld[4][2][32];
  int bh = blockIdx.y;
  int b = bh >> 4, h = bh & 15;
  int t = threadIdx.x, lane = t & 63, wave = t >> 6;
  int l31 = lane & 31, hi = lane >> 5;
  const float LOG2E = 1.44269504088896340736f;
  if (t < 33) bias_l[t] = rel_bias[t * HEADS + h] * LOG2E;

  int qw0 = blockIdx.x * 256 + wave * 64;          // this wave's 64 q-rows
  const unsigned short* Qp = Qb + (bh * SEQ + qw0) * HDIM;
  const unsigned short* Kp = Kb + bh * SEQ * HDIM;
  const unsigned short* Vp = Vt + bh * HDIM * SEQ;

  // Q fragments for both halves: col=q=l31 (+32 for B), k(d) = ks*16 + hi*8 + j
  short8 qfA[4], qfB[4];
  #pragma unroll
  for (int ks = 0; ks < 4; ++ks) {
    qfA[ks] = *(const short8*)(Qp + l31 * HDIM + ks * 16 + hi * 8);
    qfB[ks] = *(const short8*)(Qp + (32 + l31) * HDIM + ks * 16 + hi * 8);
  }

  // precomputed per-lane LDS byte offsets, shared by K and V reads:
  // row = rs*32+l31, slot = (ks*2+hi)^(row&7);  off = row*128 + slot*16
  unsigned rbo[2][4];
  #pragma unroll
  for (int rs = 0; rs < 2; ++rs)
    #pragma unroll
    for (int ks = 0; ks < 4; ++ks) {
      int row = rs * 32 + l31;
      rbo[rs][ks] = (unsigned)((row << 7) + ((((ks << 1) | hi) ^ (row & 7)) << 4));
    }
  #define LDK(rs, ks, BUF) \
    (*(const short8*)((const char*)KVs + rbo[rs][ks] + (BUF) * 8192))
  #define LDVv(rs, ks, BUF) \
    (*(const short8*)((const char*)KVs + rbo[rs][ks] + 16384 + (BUF) * 8192))

  f32x16 OA0 = {}, OA1 = {}, OB0 = {}, OB1 = {};
  float lsA0 = 0.f, lsA1 = 0.f, lsB0 = 0.f, lsB1 = 0.f;
  int qA = qw0 + l31, qB = qw0 + 32 + l31;

  // staging: wave stages rows [wave*16, wave*16+16)
  int srow0 = (wave << 4) + (lane >> 3);
  int sslot = lane & 7;

  #define STAGE(BUF, key0_)                                                          \
    for (int j = 0; j < 2; ++j) {                                                    \
      int srow = srow0 + j * 8;                                                      \
      int cs = sslot ^ (srow & 7);                                                   \
      GLOAD_LDS16(Kp + ((key0_) + srow) * HDIM + cs * 8,                             \
                  &KVs[(BUF) * 4096 + (((wave << 4) + j * 8) << 6)]);                \
      GLOAD_LDS16(Vp + srow * SEQ + (key0_) + cs * 8,                                \
                  &KVs[8192 + (BUF) * 4096 + (((wave << 4) + j * 8) << 6)]);         \
    }

  STAGE(0, 0)
  __syncthreads();
  float cbLo = bias_l[0], cbHi = bias_l[32];

  // softmax + pack + PV for one 32-key block held in acc SACC, one q-half
  #define PROC(SACC, KOFF, BUF, QW, QV, LS0, LS1, OD0, OD1)  {                       \
    float pv[16];                                                                    \
    int kbase = key0 + (KOFF);                                                       \
    if (kbase >= (QW) + 47) {                                                        \
      _Pragma("unroll") for (int r = 0; r < 16; ++r)                                 \
        pv[r] = vexp2(SACC[r] + cbHi);                                               \
    } else if (kbase <= (QW) - 47) {                                                 \
      _Pragma("unroll") for (int r = 0; r < 16; ++r)                                 \
        pv[r] = vexp2(SACC[r] + cbLo);                                               \
    } else {                                                                         \
      _Pragma("unroll") for (int r = 0; r < 16; ++r) {                               \
        int key = kbase + (r & 3) + 8 * (r >> 2) + 4 * hi;                           \
        int rel = key - (QV);                                                        \
        rel = rel < -16 ? -16 : (rel > 16 ? 16 : rel);                               \
        pv[r] = vexp2(SACC[r] + bias_l[rel + 16]);                                   \
      }                                                                              \
    }                                                                                \
    LS0 += ((pv[0] + pv[1]) + (pv[2] + pv[3])) + ((pv[4] + pv[5]) + (pv[6] + pv[7]));\
    LS1 += ((pv[8] + pv[9]) + (pv[10] + pv[11])) + ((pv[12] + pv[13]) + (pv[14] + pv[15]));\
    /* A-frag dwords: dw0={hi0:(0,1),hi1:(8,9)} dw1={hi0:(2,3),hi1:(10,11)}         \
       dw2={hi0:(4,5),hi1:(12,13)} dw3={hi0:(6,7),hi1:(14,15)} */                   \
    unsigned a0 = cvtpk(pv[0], pv[1]),  a1 = cvtpk(pv[4], pv[5]);   PLSWAP(a0, a1);  \
    unsigned a2 = cvtpk(pv[2], pv[3]),  a3 = cvtpk(pv[6], pv[7]);   PLSWAP(a2, a3);  \
    unsigned b0 = cvtpk(pv[8], pv[9]),  b1 = cvtpk(pv[12], pv[13]); PLSWAP(b0, b1);  \
    unsigned b2 = cvtpk(pv[10], pv[11]), b3 = cvtpk(pv[14], pv[15]); PLSWAP(b2, b3); \
    short8 pa0 = mk8(a0, a2, a1, a3);                                                \
    short8 pa1 = mk8(b0, b2, b1, b3);                                                \
    OD0 = __builtin_amdgcn_mfma_f32_32x32x16_bf16(pa0, LDVv(0, (KOFF)/16, BUF),     OD0, 0, 0, 0); \
    OD1 = __builtin_amdgcn_mfma_f32_32x32x16_bf16(pa0, LDVv(1, (KOFF)/16, BUF),     OD1, 0, 0, 0); \
    OD0 = __builtin_amdgcn_mfma_f32_32x32x16_bf16(pa1, LDVv(0, (KOFF)/16 + 1, BUF), OD0, 0, 0, 0); \
    OD1 = __builtin_amdgcn_mfma_f32_32x32x16_bf16(pa1, LDVv(1, (KOFF)/16 + 1, BUF), OD1, 0, 0, 0); \
  }

  // QK^T for one q-half: S[key][q], A=K rows (CSE-able LDS reads), B=Q cols
  #define QKT(BUF, QF, S0, S1)                                                       \
    f32x16 S0 = {}, S1 = {};                                                         \
    _Pragma("unroll") for (int ks = 0; ks < 4; ++ks) {                               \
      S0 = __builtin_amdgcn_mfma_f32_32x32x16_bf16(LDK(0, ks, BUF), QF[ks], S0, 0, 0, 0); \
      S1 = __builtin_amdgcn_mfma_f32_32x32x16_bf16(LDK(1, ks, BUF), QF[ks], S1, 0, 0, 0); \
    }

  #define PHASE(BUF, KEY0, DO_STAGE)  {                                              \
    int key0 = (KEY0);                                                               \
    if (DO_STAGE) { STAGE(BUF ^ 1, key0 + 64) }                                      \
    {                                                                                \
      QKT(BUF, qfA, s0, s1)                                                          \
      PROC(s0, 0,  BUF, qw0, qA, lsA0, lsA1, OA0, OA1)                               \
      PROC(s1, 32, BUF, qw0, qA, lsA0, lsA1, OA0, OA1)                               \
    }                                                                                \
    {                                                                                \
      QKT(BUF, qfB, s0, s1)                                                          \
      PROC(s0, 0,  BUF, qw0 + 32, qB, lsB0, lsB1, OB0, OB1)                          \
      PROC(s1, 32, BUF, qw0 + 32, qB, lsB0, lsB1, OB0, OB1)                          \
    }                                                                                \
    __syncthreads();                                                                 \
  }

  for (int kbp = 0; kbp < 16; ++kbp) {
    PHASE(0, (kbp * 2) * 64, 1)
    PHASE(1, (kbp * 2 + 1) * 64, kbp < 15)
  }

  // ---- epilogue: denom per q (per half), normalize, store ----
  {
    float lsum = lsA0 + lsA1;
    float denom = lsum + __shfl_xor(lsum, 32, 64);
    if (lane < 32) dld[wave][0][l31] = 1.0f / denom;
    lsum = lsB0 + lsB1;
    denom = lsum + __shfl_xor(lsum, 32, 64);
    if (lane < 32) dld[wave][1][l31] = 1.0f / denom;
  }
  float* opA = out + (b * SEQ + qw0) * EMBED + h * HDIM;
  float* opB = opA + 32 * EMBED;
  #pragma unroll
  for (int r = 0; r < 16; ++r) {
    int ql = (r & 3) + 8 * (r >> 2) + 4 * hi;
    float invA = dld[wave][0][ql];
    float invB = dld[wave][1][ql];
    opA[ql * EMBED + l31]      = OA0[r] * invA;
    opA[ql * EMBED + 32 + l31] = OA1[r] * invA;
    opB[ql * EMBED + l31]      = OB0[r] * invB;
    opB[ql * EMBED + 32 + l31] = OB1[r] * invB;
  }
  #undef STAGE
  #undef LDK
  #undef LDVv
  #undef PROC
  #undef QKT
  #undef PHASE
}

extern "C" void kernel_launch(void* const* d_in, const int* in_sizes, int n_in,
                              void* d_out, int out_size, void* d_ws, size_t ws_size,
                              hipStream_t stream) {
  const float* x        = (const float*)d_in[0];
  const float* Wq       = (const float*)d_in[1];
  const float* bq       = (const float*)d_in[2];
  const float* Wk       = (const float*)d_in[3];
  const float* bk       = (const float*)d_in[4];
  const float* Wv       = (const float*)d_in[5];
  const float* bv       = (const float*)d_in[6];
  const float* rel_bias = (const float*)d_in[7];
  float* out = (float*)d_out;

  char* ws = (char*)d_ws;
  unsigned short* xb  = (unsigned short*)(ws);                 // 16 MB
  unsigned short* Wtb = (unsigned short*)(ws + 16777216);      // 6 MB
  unsigned short* Qb  = (unsigned short*)(ws + 23068672);      // 16 MB
  unsigned short* Kb  = (unsigned short*)(ws + 39845888);      // 16 MB
  unsigned short* Vt  = (unsigned short*)(ws + 56623104);      // 16 MB (total 70 MB)

  cvt_x<<<MTOT * EMBED / (256 * 8), 256, 0, stream>>>(x, xb);
  transpose_w<<<dim3(32, 32, 3), 256, 0, stream>>>(Wq, Wk, Wv, Wtb);
  qkv_gemm<<<dim3(MTOT / 128, EMBED / 128, 3), 256, 0, stream>>>(xb, Wtb, bq, bk, bv, Qb, Kb, Vt);
  attn<<<dim3(SEQ / 256, BATCH * HEADS), 256, 0, stream>>>(Qb, Kb, Vt, rel_bias, out);
}

// Round 13
// 207.521 us; speedup vs baseline: 1.1565x; 1.1565x over previous
//
#include <hip/hip_runtime.h>

#define EMBED 1024
#define HEADS 16
#define HDIM  64
#define SEQ   2048
#define BATCH 4
#define MTOT  (BATCH*SEQ)

typedef __attribute__((ext_vector_type(8)))  short short8;
typedef __attribute__((ext_vector_type(4)))  float f32x4;
typedef __attribute__((ext_vector_type(16))) float f32x16;

#define GLOAD_LDS16(g, l) \
  __builtin_amdgcn_global_load_lds((const __attribute__((address_space(1))) void*)(g), \
                                   (__attribute__((address_space(3))) void*)(l), 16, 0, 0)

__device__ inline unsigned short f2bf(float f) {
  union { float f; unsigned u; } v; v.f = f;
  unsigned r = v.u + 0x7FFF + ((v.u >> 16) & 1);
  return (unsigned short)(r >> 16);
}

__device__ inline unsigned cvtpk(float lo, float hi) {
  unsigned r;
  asm("v_cvt_pk_bf16_f32 %0, %1, %2" : "=v"(r) : "v"(lo), "v"(hi));
  return r;
}

// raw 2^x — single trans-pipe instr; inputs bounded (|x| < ~8), no edge cases
__device__ inline float vexp2(float x) {
  float r;
  asm("v_exp_f32 %0, %1" : "=v"(r) : "v"(x));
  return r;
}

// v_permlane32_swap_b32 vdst, vsrc — HW semantics (R6/R7 falsification test):
// new vdst[32:63] = old vsrc[0:31]; new vsrc[0:31] = old vdst[32:63].
#define PLSWAP(a, b) asm("v_permlane32_swap_b32 %0, %1" : "+v"(a), "+v"(b))

__device__ inline short8 mk8(unsigned w0, unsigned w1, unsigned w2, unsigned w3) {
  union { unsigned u[4]; short8 s; } x;
  x.u[0] = w0; x.u[1] = w1; x.u[2] = w2; x.u[3] = w3;
  return x.s;
}

// ---------- kernel 1: x fp32 -> bf16 ----------
__global__ void cvt_x(const float* __restrict__ x, unsigned short* __restrict__ xb) {
  int i = (blockIdx.x * blockDim.x + threadIdx.x) * 8;
  f32x4 a = *(const f32x4*)(x + i);
  f32x4 b = *(const f32x4*)(x + i + 4);
  unsigned short o[8];
  o[0]=f2bf(a[0]); o[1]=f2bf(a[1]); o[2]=f2bf(a[2]); o[3]=f2bf(a[3]);
  o[4]=f2bf(b[0]); o[5]=f2bf(b[1]); o[6]=f2bf(b[2]); o[7]=f2bf(b[3]);
  *(short8*)(xb + i) = *(short8*)o;
}

// ---------- kernel 2: W [K][N] fp32 -> Wt [N][K] bf16 (x3) ----------
__global__ void transpose_w(const float* __restrict__ Wq, const float* __restrict__ Wk,
                            const float* __restrict__ Wv, unsigned short* __restrict__ Wtb) {
  __shared__ float tile[32][33];
  int wsel = blockIdx.z;
  const float* W = wsel == 0 ? Wq : (wsel == 1 ? Wk : Wv);
  int k0 = blockIdx.x * 32, n0 = blockIdx.y * 32;
  int tx = threadIdx.x & 31, ty = threadIdx.x >> 5;
  for (int i = 0; i < 4; ++i)
    tile[ty + i*8][tx] = W[(k0 + ty + i*8) * EMBED + n0 + tx];
  __syncthreads();
  unsigned short* o = Wtb + wsel * EMBED * EMBED;
  for (int i = 0; i < 4; ++i)
    o[(n0 + ty + i*8) * EMBED + k0 + tx] = f2bf(tile[tx][ty + i*8]);
}

// ---------- kernel 3: QKV projection GEMM ----------
// Q output is pre-scaled by 0.125*log2(e) so attn's softmax needs no per-score FMA.
__global__ __launch_bounds__(256)
void qkv_gemm(const unsigned short* __restrict__ xb, const unsigned short* __restrict__ Wtb,
              const float* __restrict__ bq, const float* __restrict__ bk, const float* __restrict__ bv,
              unsigned short* __restrict__ Qb, unsigned short* __restrict__ Kb,
              unsigned short* __restrict__ Vt) {
  __shared__ unsigned short As[128 * 72];
  __shared__ unsigned short Bs[128 * 72];
  int wsel = blockIdx.z;
  int m0 = blockIdx.x * 128, n0 = blockIdx.y * 128;
  int t = threadIdx.x, lane = t & 63, wave = t >> 6;
  int wr = wave >> 1, wc = wave & 1;
  int lr = lane & 15, lg = lane >> 4;
  const unsigned short* Wt = Wtb + wsel * (EMBED * EMBED);
  const float* bias = wsel == 0 ? bq : (wsel == 1 ? bk : bv);

  f32x4 acc[4][4] = {};

  for (int kt = 0; kt < EMBED / 64; ++kt) {
    int k0 = kt * 64;
    for (int i = 0; i < 4; ++i) {
      int c = i * 256 + t;
      int row = c >> 3, col8 = c & 7;
      short8 va = *(const short8*)(xb + (m0 + row) * EMBED + k0 + col8 * 8);
      short8 vb = *(const short8*)(Wt + (n0 + row) * EMBED + k0 + col8 * 8);
      *(short8*)(As + row * 72 + col8 * 8) = va;
      *(short8*)(Bs + row * 72 + col8 * 8) = vb;
    }
    __syncthreads();
    for (int kk = 0; kk < 2; ++kk) {
      short8 af[4], bfr[4];
      for (int mf = 0; mf < 4; ++mf)
        af[mf] = *(const short8*)(As + (wr * 64 + mf * 16 + lr) * 72 + kk * 32 + lg * 8);
      for (int nf = 0; nf < 4; ++nf)
        bfr[nf] = *(const short8*)(Bs + (wc * 64 + nf * 16 + lr) * 72 + kk * 32 + lg * 8);
      for (int mf = 0; mf < 4; ++mf)
        for (int nf = 0; nf < 4; ++nf)
          acc[mf][nf] = __builtin_amdgcn_mfma_f32_16x16x32_bf16(af[mf], bfr[nf], acc[mf][nf], 0, 0, 0);
    }
    __syncthreads();
  }

  const float SCLQ = 0.125f * 1.44269504088896340736f;
  for (int nf = 0; nf < 4; ++nf) {
    int n = n0 + wc * 64 + nf * 16 + lr;
    float bval = bias[n];
    int h = n >> 6, d = n & 63;
    for (int mf = 0; mf < 4; ++mf) {
      for (int r = 0; r < 4; ++r) {
        int m = m0 + wr * 64 + mf * 16 + lg * 4 + r;
        int b = m >> 11, s = m & 2047;
        float oval = acc[mf][nf][r] + bval;
        if (wsel == 0) oval *= SCLQ;   // wave-uniform branch
        unsigned short bfv = f2bf(oval);
        if (wsel == 0)      Qb[((b * HEADS + h) * SEQ + s) * HDIM + d] = bfv;
        else if (wsel == 1) Kb[((b * HEADS + h) * SEQ + s) * HDIM + d] = bfv;
        else                Vt[((b * HEADS + h) * HDIM + d) * SEQ + s] = bfv;
      }
    }
  }
}

// ---------- kernel 4: flash attention, 32x32 MFMA, swapped QK^T ----------
// R11 structure (32 q/wave, 4 waves, KVBLK=64, dbuf) with register-pressure fix:
// the two 32-key S-chains are computed AND consumed one at a time, separated by
// sched_barrier(0), so peak live acc state is 16 (S) + 32 (O) not 32+32.
// R12 lesson: total VGPR+AGPR is the occupancy limiter (108->176 halved waves).
__global__ __launch_bounds__(256)
void attn(const unsigned short* __restrict__ Qb, const unsigned short* __restrict__ Kb,
          const unsigned short* __restrict__ Vt, const float* __restrict__ rel_bias,
          float* __restrict__ out) {
  __shared__ unsigned short KVs[16384];   // K buf0 | K buf1 | V buf0 | V buf1 (4096 ea)
  __shared__ float bias_l[33];
  __shared__ float dld[4][32];
  int bh = blockIdx.y;
  int b = bh >> 4, h = bh & 15;
  int t = threadIdx.x, lane = t & 63, wave = t >> 6;
  int l31 = lane & 31, hi = lane >> 5;
  const float LOG2E = 1.44269504088896340736f;
  if (t < 33) bias_l[t] = rel_bias[t * HEADS + h] * LOG2E;

  int qw0 = blockIdx.x * 128 + wave * 32;          // this wave's 32 q-rows
  const unsigned short* Qp = Qb + (bh * SEQ + qw0) * HDIM;
  const unsigned short* Kp = Kb + bh * SEQ * HDIM;
  const unsigned short* Vp = Vt + bh * HDIM * SEQ;

  // Q as B-operand fragments: col=q=l31, k(d) = ks*16 + hi*8 + j
  short8 qf[4];
  #pragma unroll
  for (int ks = 0; ks < 4; ++ks)
    qf[ks] = *(const short8*)(Qp + l31 * HDIM + ks * 16 + hi * 8);

  // precomputed per-lane LDS byte offsets, shared by K and V reads:
  // row = rs*32+l31, slot = (ks*2+hi)^(row&7);  off = row*128 + slot*16
  unsigned rbo[2][4];
  #pragma unroll
  for (int rs = 0; rs < 2; ++rs)
    #pragma unroll
    for (int ks = 0; ks < 4; ++ks) {
      int row = rs * 32 + l31;
      rbo[rs][ks] = (unsigned)((row << 7) + ((((ks << 1) | hi) ^ (row & 7)) << 4));
    }
  #define LDK(rs, ks, BUF) \
    (*(const short8*)((const char*)KVs + rbo[rs][ks] + (BUF) * 8192))
  #define LDVv(rs, ks, BUF) \
    (*(const short8*)((const char*)KVs + rbo[rs][ks] + 16384 + (BUF) * 8192))

  f32x16 O0 = {}, O1 = {};
  float ls0 = 0.f, ls1 = 0.f;
  int q = qw0 + l31;

  // staging: wave stages rows [wave*16, wave*16+16)
  int srow0 = (wave << 4) + (lane >> 3);
  int sslot = lane & 7;

  #define STAGE(BUF, key0_)                                                          \
    for (int j = 0; j < 2; ++j) {                                                    \
      int srow = srow0 + j * 8;                                                      \
      int cs = sslot ^ (srow & 7);                                                   \
      GLOAD_LDS16(Kp + ((key0_) + srow) * HDIM + cs * 8,                             \
                  &KVs[(BUF) * 4096 + (((wave << 4) + j * 8) << 6)]);                \
      GLOAD_LDS16(Vp + srow * SEQ + (key0_) + cs * 8,                                \
                  &KVs[8192 + (BUF) * 4096 + (((wave << 4) + j * 8) << 6)]);         \
    }

  STAGE(0, 0)
  __syncthreads();
  float cbLo = bias_l[0], cbHi = bias_l[32];

  // softmax + pack + PV for one 32-key block held in acc SACC
  #define PROC(SACC, KOFF, BUF)  {                                                   \
    float pv[16];                                                                    \
    int kbase = key0 + (KOFF);                                                       \
    if (kbase >= qw0 + 47) {                                                         \
      _Pragma("unroll") for (int r = 0; r < 16; ++r)                                 \
        pv[r] = vexp2(SACC[r] + cbHi);                                               \
    } else if (kbase <= qw0 - 47) {                                                  \
      _Pragma("unroll") for (int r = 0; r < 16; ++r)                                 \
        pv[r] = vexp2(SACC[r] + cbLo);                                               \
    } else {                                                                         \
      _Pragma("unroll") for (int r = 0; r < 16; ++r) {                               \
        int key = kbase + (r & 3) + 8 * (r >> 2) + 4 * hi;                           \
        int rel = key - q;                                                           \
        rel = rel < -16 ? -16 : (rel > 16 ? 16 : rel);                               \
        pv[r] = vexp2(SACC[r] + bias_l[rel + 16]);                                   \
      }                                                                              \
    }                                                                                \
    ls0 += ((pv[0] + pv[1]) + (pv[2] + pv[3])) + ((pv[4] + pv[5]) + (pv[6] + pv[7]));\
    ls1 += ((pv[8] + pv[9]) + (pv[10] + pv[11])) + ((pv[12] + pv[13]) + (pv[14] + pv[15]));\
    /* A-frag dwords: dw0={hi0:(0,1),hi1:(8,9)} dw1={hi0:(2,3),hi1:(10,11)}         \
       dw2={hi0:(4,5),hi1:(12,13)} dw3={hi0:(6,7),hi1:(14,15)} */                   \
    unsigned a0 = cvtpk(pv[0], pv[1]),  a1 = cvtpk(pv[4], pv[5]);   PLSWAP(a0, a1);  \
    unsigned a2 = cvtpk(pv[2], pv[3]),  a3 = cvtpk(pv[6], pv[7]);   PLSWAP(a2, a3);  \
    unsigned b0 = cvtpk(pv[8], pv[9]),  b1 = cvtpk(pv[12], pv[13]); PLSWAP(b0, b1);  \
    unsigned b2 = cvtpk(pv[10], pv[11]), b3 = cvtpk(pv[14], pv[15]); PLSWAP(b2, b3); \
    short8 pa0 = mk8(a0, a2, a1, a3);                                                \
    short8 pa1 = mk8(b0, b2, b1, b3);                                                \
    O0 = __builtin_amdgcn_mfma_f32_32x32x16_bf16(pa0, LDVv(0, (KOFF)/16, BUF),     O0, 0, 0, 0); \
    O1 = __builtin_amdgcn_mfma_f32_32x32x16_bf16(pa0, LDVv(1, (KOFF)/16, BUF),     O1, 0, 0, 0); \
    O0 = __builtin_amdgcn_mfma_f32_32x32x16_bf16(pa1, LDVv(0, (KOFF)/16 + 1, BUF), O0, 0, 0, 0); \
    O1 = __builtin_amdgcn_mfma_f32_32x32x16_bf16(pa1, LDVv(1, (KOFF)/16 + 1, BUF), O1, 0, 0, 0); \
  }

  // One 32-key half: QK^T chain then its softmax+PV, as a closed region.
  #define HALF(RS, KOFF, BUF)  {                                                     \
    f32x16 s_ = {};                                                                  \
    _Pragma("unroll") for (int ks = 0; ks < 4; ++ks)                                 \
      s_ = __builtin_amdgcn_mfma_f32_32x32x16_bf16(LDK(RS, ks, BUF), qf[ks], s_, 0, 0, 0); \
    PROC(s_, KOFF, BUF)                                                              \
  }

  #define PHASE(BUF, KEY0, DO_STAGE)  {                                              \
    int key0 = (KEY0);                                                               \
    if (DO_STAGE) { STAGE(BUF ^ 1, key0 + 64) }                                      \
    HALF(0, 0, BUF)                                                                  \
    __builtin_amdgcn_sched_barrier(0);   /* cap live regs: one S-chain at a time */  \
    HALF(1, 32, BUF)                                                                 \
    __syncthreads();                                                                 \
  }

  for (int kbp = 0; kbp < 16; ++kbp) {
    PHASE(0, (kbp * 2) * 64, 1)
    PHASE(1, (kbp * 2 + 1) * 64, kbp < 15)
  }

  // ---- epilogue: denom per q, normalize, store ----
  float lsum = ls0 + ls1;
  float denom = lsum + __shfl_xor(lsum, 32, 64);
  if (lane < 32) dld[wave][l31] = 1.0f / denom;   // wave-local, wave-synchronous
  float* op = out + (b * SEQ + qw0) * EMBED + h * HDIM;
  #pragma unroll
  for (int r = 0; r < 16; ++r) {
    int ql = (r & 3) + 8 * (r >> 2) + 4 * hi;
    float inv = dld[wave][ql];
    op[ql * EMBED + l31]      = O0[r] * inv;
    op[ql * EMBED + 32 + l31] = O1[r] * inv;
  }
  #undef STAGE
  #undef LDK
  #undef LDVv
  #undef PROC
  #undef HALF
  #undef PHASE
}

extern "C" void kernel_launch(void* const* d_in, const int* in_sizes, int n_in,
                              void* d_out, int out_size, void* d_ws, size_t ws_size,
                              hipStream_t stream) {
  const float* x        = (const float*)d_in[0];
  const float* Wq       = (const float*)d_in[1];
  const float* bq       = (const float*)d_in[2];
  const float* Wk       = (const float*)d_in[3];
  const float* bk       = (const float*)d_in[4];
  const float* Wv       = (const float*)d_in[5];
  const float* bv       = (const float*)d_in[6];
  const float* rel_bias = (const float*)d_in[7];
  float* out = (float*)d_out;

  char* ws = (char*)d_ws;
  unsigned short* xb  = (unsigned short*)(ws);                 // 16 MB
  unsigned short* Wtb = (unsigned short*)(ws + 16777216);      // 6 MB
  unsigned short* Qb  = (unsigned short*)(ws + 23068672);      // 16 MB
  unsigned short* Kb  = (unsigned short*)(ws + 39845888);      // 16 MB
  unsigned short* Vt  = (unsigned short*)(ws + 56623104);      // 16 MB (total 70 MB)

  cvt_x<<<MTOT * EMBED / (256 * 8), 256, 0, stream>>>(x, xb);
  transpose_w<<<dim3(32, 32, 3), 256, 0, stream>>>(Wq, Wk, Wv, Wtb);
  qkv_gemm<<<dim3(MTOT / 128, EMBED / 128, 3), 256, 0, stream>>>(xb, Wtb, bq, bk, bv, Qb, Kb, Vt);
  attn<<<dim3(SEQ / 128, BATCH * HEADS), 256, 0, stream>>>(Qb, Kb, Vt, rel_bias, out);
}

// Round 14
// 203.256 us; speedup vs baseline: 1.1808x; 1.0210x over previous
//
#include <hip/hip_runtime.h>

#define EMBED 1024
#define HEADS 16
#define HDIM  64
#define SEQ   2048
#define BATCH 4
#define MTOT  (BATCH*SEQ)

typedef __attribute__((ext_vector_type(8)))  short short8;
typedef __attribute__((ext_vector_type(4)))  float f32x4;
typedef __attribute__((ext_vector_type(16))) float f32x16;

#define GLOAD_LDS16(g, l) \
  __builtin_amdgcn_global_load_lds((const __attribute__((address_space(1))) void*)(g), \
                                   (__attribute__((address_space(3))) void*)(l), 16, 0, 0)

__device__ inline unsigned short f2bf(float f) {
  union { float f; unsigned u; } v; v.f = f;
  unsigned r = v.u + 0x7FFF + ((v.u >> 16) & 1);
  return (unsigned short)(r >> 16);
}

__device__ inline unsigned cvtpk(float lo, float hi) {
  unsigned r;
  asm("v_cvt_pk_bf16_f32 %0, %1, %2" : "=v"(r) : "v"(lo), "v"(hi));
  return r;
}

// raw 2^x — single trans-pipe instr; inputs bounded (|x| < ~8), no edge cases
__device__ inline float vexp2(float x) {
  float r;
  asm("v_exp_f32 %0, %1" : "=v"(r) : "v"(x));
  return r;
}

// v_permlane32_swap_b32 vdst, vsrc — HW semantics (R6/R7 falsification test):
// new vdst[32:63] = old vsrc[0:31]; new vsrc[0:31] = old vdst[32:63].
#define PLSWAP(a, b) asm("v_permlane32_swap_b32 %0, %1" : "+v"(a), "+v"(b))

__device__ inline short8 mk8(unsigned w0, unsigned w1, unsigned w2, unsigned w3) {
  union { unsigned u[4]; short8 s; } x;
  x.u[0] = w0; x.u[1] = w1; x.u[2] = w2; x.u[3] = w3;
  return x.s;
}

// ---------- kernel 1: x fp32 -> bf16 ----------
__global__ void cvt_x(const float* __restrict__ x, unsigned short* __restrict__ xb) {
  int i = (blockIdx.x * blockDim.x + threadIdx.x) * 8;
  f32x4 a = *(const f32x4*)(x + i);
  f32x4 b = *(const f32x4*)(x + i + 4);
  unsigned short o[8];
  o[0]=f2bf(a[0]); o[1]=f2bf(a[1]); o[2]=f2bf(a[2]); o[3]=f2bf(a[3]);
  o[4]=f2bf(b[0]); o[5]=f2bf(b[1]); o[6]=f2bf(b[2]); o[7]=f2bf(b[3]);
  *(short8*)(xb + i) = *(short8*)o;
}

// ---------- kernel 2: W [K][N] fp32 -> Wt [N][K] bf16 (x3) ----------
__global__ void transpose_w(const float* __restrict__ Wq, const float* __restrict__ Wk,
                            const float* __restrict__ Wv, unsigned short* __restrict__ Wtb) {
  __shared__ float tile[32][33];
  int wsel = blockIdx.z;
  const float* W = wsel == 0 ? Wq : (wsel == 1 ? Wk : Wv);
  int k0 = blockIdx.x * 32, n0 = blockIdx.y * 32;
  int tx = threadIdx.x & 31, ty = threadIdx.x >> 5;
  for (int i = 0; i < 4; ++i)
    tile[ty + i*8][tx] = W[(k0 + ty + i*8) * EMBED + n0 + tx];
  __syncthreads();
  unsigned short* o = Wtb + wsel * EMBED * EMBED;
  for (int i = 0; i < 4; ++i)
    o[(n0 + ty + i*8) * EMBED + k0 + tx] = f2bf(tile[tx][ty + i*8]);
}

// ---------- kernel 3: QKV projection GEMM ----------
// Q output is pre-scaled by 0.125*log2(e) so attn's softmax needs no per-score FMA.
__global__ __launch_bounds__(256)
void qkv_gemm(const unsigned short* __restrict__ xb, const unsigned short* __restrict__ Wtb,
              const float* __restrict__ bq, const float* __restrict__ bk, const float* __restrict__ bv,
              unsigned short* __restrict__ Qb, unsigned short* __restrict__ Kb,
              unsigned short* __restrict__ Vt) {
  __shared__ unsigned short As[128 * 72];
  __shared__ unsigned short Bs[128 * 72];
  int wsel = blockIdx.z;
  int m0 = blockIdx.x * 128, n0 = blockIdx.y * 128;
  int t = threadIdx.x, lane = t & 63, wave = t >> 6;
  int wr = wave >> 1, wc = wave & 1;
  int lr = lane & 15, lg = lane >> 4;
  const unsigned short* Wt = Wtb + wsel * (EMBED * EMBED);
  const float* bias = wsel == 0 ? bq : (wsel == 1 ? bk : bv);

  f32x4 acc[4][4] = {};

  for (int kt = 0; kt < EMBED / 64; ++kt) {
    int k0 = kt * 64;
    for (int i = 0; i < 4; ++i) {
      int c = i * 256 + t;
      int row = c >> 3, col8 = c & 7;
      short8 va = *(const short8*)(xb + (m0 + row) * EMBED + k0 + col8 * 8);
      short8 vb = *(const short8*)(Wt + (n0 + row) * EMBED + k0 + col8 * 8);
      *(short8*)(As + row * 72 + col8 * 8) = va;
      *(short8*)(Bs + row * 72 + col8 * 8) = vb;
    }
    __syncthreads();
    for (int kk = 0; kk < 2; ++kk) {
      short8 af[4], bfr[4];
      for (int mf = 0; mf < 4; ++mf)
        af[mf] = *(const short8*)(As + (wr * 64 + mf * 16 + lr) * 72 + kk * 32 + lg * 8);
      for (int nf = 0; nf < 4; ++nf)
        bfr[nf] = *(const short8*)(Bs + (wc * 64 + nf * 16 + lr) * 72 + kk * 32 + lg * 8);
      for (int mf = 0; mf < 4; ++mf)
        for (int nf = 0; nf < 4; ++nf)
          acc[mf][nf] = __builtin_amdgcn_mfma_f32_16x16x32_bf16(af[mf], bfr[nf], acc[mf][nf], 0, 0, 0);
    }
    __syncthreads();
  }

  const float SCLQ = 0.125f * 1.44269504088896340736f;
  for (int nf = 0; nf < 4; ++nf) {
    int n = n0 + wc * 64 + nf * 16 + lr;
    float bval = bias[n];
    int h = n >> 6, d = n & 63;
    for (int mf = 0; mf < 4; ++mf) {
      for (int r = 0; r < 4; ++r) {
        int m = m0 + wr * 64 + mf * 16 + lg * 4 + r;
        int b = m >> 11, s = m & 2047;
        float oval = acc[mf][nf][r] + bval;
        if (wsel == 0) oval *= SCLQ;   // wave-uniform branch
        unsigned short bfv = f2bf(oval);
        if (wsel == 0)      Qb[((b * HEADS + h) * SEQ + s) * HDIM + d] = bfv;
        else if (wsel == 1) Kb[((b * HEADS + h) * SEQ + s) * HDIM + d] = bfv;
        else                Vt[((b * HEADS + h) * HDIM + d) * SEQ + s] = bfv;
      }
    }
  }
}

// ---------- kernel 4: flash attention, 32x32 MFMA, swapped QK^T ----------
// T3/T4: triple-buffered K/V staged 2 tiles ahead; per phase the wave waits
// s_waitcnt vmcnt(4) (own next-tile loads done, newest 4 stay in flight) then
// raw s_barrier — the vmcnt(0) drain __syncthreads would emit never happens
// in the main loop. Loop unrolled x3 so buffer offsets are immediates.
__global__ __launch_bounds__(256)
void attn(const unsigned short* __restrict__ Qb, const unsigned short* __restrict__ Kb,
          const unsigned short* __restrict__ Vt, const float* __restrict__ rel_bias,
          float* __restrict__ out) {
  __shared__ unsigned short KVs[24576];   // K0|K1|K2|V0|V1|V2, 4096 shorts each... (bytes: 6*4096*2=48KB? no—shorts)
  __shared__ float bias_l[33];
  __shared__ float dld[4][32];
  int bh = blockIdx.y;
  int b = bh >> 4, h = bh & 15;
  int t = threadIdx.x, lane = t & 63, wave = t >> 6;
  int l31 = lane & 31, hi = lane >> 5;
  const float LOG2E = 1.44269504088896340736f;
  if (t < 33) bias_l[t] = rel_bias[t * HEADS + h] * LOG2E;

  int qw0 = blockIdx.x * 128 + wave * 32;          // this wave's 32 q-rows
  const unsigned short* Qp = Qb + (bh * SEQ + qw0) * HDIM;
  const unsigned short* Kp = Kb + bh * SEQ * HDIM;
  const unsigned short* Vp = Vt + bh * HDIM * SEQ;

  // Q as B-operand fragments: col=q=l31, k(d) = ks*16 + hi*8 + j
  short8 qf[4];
  #pragma unroll
  for (int ks = 0; ks < 4; ++ks)
    qf[ks] = *(const short8*)(Qp + l31 * HDIM + ks * 16 + hi * 8);

  // precomputed per-lane LDS byte offsets, shared by K and V reads:
  // row = rs*32+l31, slot = (ks*2+hi)^(row&7);  off = row*128 + slot*16
  unsigned rbo[2][4];
  #pragma unroll
  for (int rs = 0; rs < 2; ++rs)
    #pragma unroll
    for (int ks = 0; ks < 4; ++ks) {
      int row = rs * 32 + l31;
      rbo[rs][ks] = (unsigned)((row << 7) + ((((ks << 1) | hi) ^ (row & 7)) << 4));
    }
  // byte layout: K buf i at i*8192; V buf i at 24576 + i*8192  (each tile 8 KB)
  #define LDK(rs, ks, BUF) \
    (*(const short8*)((const char*)KVs + rbo[rs][ks] + (BUF) * 8192))
  #define LDVv(rs, ks, BUF) \
    (*(const short8*)((const char*)KVs + rbo[rs][ks] + 24576 + (BUF) * 8192))

  f32x16 O0 = {}, O1 = {};
  float ls0 = 0.f, ls1 = 0.f;
  int q = qw0 + l31;

  // staging: wave stages rows [wave*16, wave*16+16)
  int srow0 = (wave << 4) + (lane >> 3);
  int sslot = lane & 7;

  #define STAGE(BUF, key0_)                                                          \
    for (int j = 0; j < 2; ++j) {                                                    \
      int srow = srow0 + j * 8;                                                      \
      int cs = sslot ^ (srow & 7);                                                   \
      GLOAD_LDS16(Kp + ((key0_) + srow) * HDIM + cs * 8,                             \
                  (char*)KVs + (BUF) * 8192 + ((((wave << 4) + j * 8) << 6) << 1));  \
      GLOAD_LDS16(Vp + srow * SEQ + (key0_) + cs * 8,                                \
                  (char*)KVs + 24576 + (BUF) * 8192 + ((((wave << 4) + j * 8) << 6) << 1)); \
    }

  #define WAITV4 asm volatile("s_waitcnt vmcnt(4)" ::: "memory");
  #define WAITV0 asm volatile("s_waitcnt vmcnt(0)" ::: "memory");
  #define BAR    __builtin_amdgcn_s_barrier();

  float cbLo, cbHi;

  // softmax + pack + PV for one 32-key block held in acc SACC
  #define PROC(SACC, KOFF, BUF)  {                                                   \
    float pv[16];                                                                    \
    int kbase = key0 + (KOFF);                                                       \
    if (kbase >= qw0 + 47) {                                                         \
      _Pragma("unroll") for (int r = 0; r < 16; ++r)                                 \
        pv[r] = vexp2(SACC[r] + cbHi);                                               \
    } else if (kbase <= qw0 - 47) {                                                  \
      _Pragma("unroll") for (int r = 0; r < 16; ++r)                                 \
        pv[r] = vexp2(SACC[r] + cbLo);                                               \
    } else {                                                                         \
      _Pragma("unroll") for (int r = 0; r < 16; ++r) {                               \
        int key = kbase + (r & 3) + 8 * (r >> 2) + 4 * hi;                           \
        int rel = key - q;                                                           \
        rel = rel < -16 ? -16 : (rel > 16 ? 16 : rel);                               \
        pv[r] = vexp2(SACC[r] + bias_l[rel + 16]);                                   \
      }                                                                              \
    }                                                                                \
    ls0 += ((pv[0] + pv[1]) + (pv[2] + pv[3])) + ((pv[4] + pv[5]) + (pv[6] + pv[7]));\
    ls1 += ((pv[8] + pv[9]) + (pv[10] + pv[11])) + ((pv[12] + pv[13]) + (pv[14] + pv[15]));\
    unsigned a0 = cvtpk(pv[0], pv[1]),  a1 = cvtpk(pv[4], pv[5]);   PLSWAP(a0, a1);  \
    unsigned a2 = cvtpk(pv[2], pv[3]),  a3 = cvtpk(pv[6], pv[7]);   PLSWAP(a2, a3);  \
    unsigned b0 = cvtpk(pv[8], pv[9]),  b1 = cvtpk(pv[12], pv[13]); PLSWAP(b0, b1);  \
    unsigned b2 = cvtpk(pv[10], pv[11]), b3 = cvtpk(pv[14], pv[15]); PLSWAP(b2, b3); \
    short8 pa0 = mk8(a0, a2, a1, a3);                                                \
    short8 pa1 = mk8(b0, b2, b1, b3);                                                \
    O0 = __builtin_amdgcn_mfma_f32_32x32x16_bf16(pa0, LDVv(0, (KOFF)/16, BUF),     O0, 0, 0, 0); \
    O1 = __builtin_amdgcn_mfma_f32_32x32x16_bf16(pa0, LDVv(1, (KOFF)/16, BUF),     O1, 0, 0, 0); \
    O0 = __builtin_amdgcn_mfma_f32_32x32x16_bf16(pa1, LDVv(0, (KOFF)/16 + 1, BUF), O0, 0, 0, 0); \
    O1 = __builtin_amdgcn_mfma_f32_32x32x16_bf16(pa1, LDVv(1, (KOFF)/16 + 1, BUF), O1, 0, 0, 0); \
  }

  // One 32-key half: QK^T chain then its softmax+PV, as a closed region.
  #define HALF(RS, KOFF, BUF)  {                                                     \
    f32x16 s_ = {};                                                                  \
    _Pragma("unroll") for (int ks = 0; ks < 4; ++ks)                                 \
      s_ = __builtin_amdgcn_mfma_f32_32x32x16_bf16(LDK(RS, ks, BUF), qf[ks], s_, 0, 0, 0); \
    PROC(s_, KOFF, BUF)                                                              \
  }

  #define COMPUTE(BUF, KEY0)  {                                                      \
    int key0 = (KEY0);                                                               \
    HALF(0, 0, BUF)                                                                  \
    HALF(1, 32, BUF)                                                                 \
  }

  // prologue: stage tiles 0,1; wait tile 0; barrier (also covers bias_l)
  STAGE(0, 0)
  STAGE(1, 64)
  WAITV4
  __syncthreads();
  cbLo = bias_l[0]; cbHi = bias_l[32];

  // main: 30 phases in 10 x3-unrolled iterations; tiles kb+2 staged each phase
  for (int i = 0; i < 10; ++i) {
    int t3 = i * 3;
    STAGE(2, (t3 + 2) * 64)  COMPUTE(0, t3 * 64)        WAITV4 BAR
    STAGE(0, (t3 + 3) * 64)  COMPUTE(1, (t3 + 1) * 64)  WAITV4 BAR
    STAGE(1, (t3 + 4) * 64)  COMPUTE(2, (t3 + 2) * 64)  WAITV4 BAR
  }
  // tail: tiles 30, 31 (no more staging; drain)
  COMPUTE(0, 30 * 64)
  WAITV0 BAR
  COMPUTE(1, 31 * 64)

  // ---- epilogue: denom per q, normalize, store ----
  float lsum = ls0 + ls1;
  float denom = lsum + __shfl_xor(lsum, 32, 64);
  if (lane < 32) dld[wave][l31] = 1.0f / denom;   // wave-local, wave-synchronous
  float* op = out + (b * SEQ + qw0) * EMBED + h * HDIM;
  #pragma unroll
  for (int r = 0; r < 16; ++r) {
    int ql = (r & 3) + 8 * (r >> 2) + 4 * hi;
    float inv = dld[wave][ql];
    op[ql * EMBED + l31]      = O0[r] * inv;
    op[ql * EMBED + 32 + l31] = O1[r] * inv;
  }
  #undef STAGE
  #undef LDK
  #undef LDVv
  #undef PROC
  #undef HALF
  #undef COMPUTE
}

extern "C" void kernel_launch(void* const* d_in, const int* in_sizes, int n_in,
                              void* d_out, int out_size, void* d_ws, size_t ws_size,
                              hipStream_t stream) {
  const float* x        = (const float*)d_in[0];
  const float* Wq       = (const float*)d_in[1];
  const float* bq       = (const float*)d_in[2];
  const float* Wk       = (const float*)d_in[3];
  const float* bk       = (const float*)d_in[4];
  const float* Wv       = (const float*)d_in[5];
  const float* bv       = (const float*)d_in[6];
  const float* rel_bias = (const float*)d_in[7];
  float* out = (float*)d_out;

  char* ws = (char*)d_ws;
  unsigned short* xb  = (unsigned short*)(ws);                 // 16 MB
  unsigned short* Wtb = (unsigned short*)(ws + 16777216);      // 6 MB
  unsigned short* Qb  = (unsigned short*)(ws + 23068672);      // 16 MB
  unsigned short* Kb  = (unsigned short*)(ws + 39845888);      // 16 MB
  unsigned short* Vt  = (unsigned short*)(ws + 56623104);      // 16 MB (total 70 MB)

  cvt_x<<<MTOT * EMBED / (256 * 8), 256, 0, stream>>>(x, xb);
  transpose_w<<<dim3(32, 32, 3), 256, 0, stream>>>(Wq, Wk, Wv, Wtb);
  qkv_gemm<<<dim3(MTOT / 128, EMBED / 128, 3), 256, 0, stream>>>(xb, Wtb, bq, bk, bv, Qb, Kb, Vt);
  attn<<<dim3(SEQ / 128, BATCH * HEADS), 256, 0, stream>>>(Qb, Kb, Vt, rel_bias, out);
}

// Round 16
// 198.800 us; speedup vs baseline: 1.2073x; 1.0224x over previous
//
#include <hip/hip_runtime.h>

#define EMBED 1024
#define HEADS 16
#define HDIM  64
#define SEQ   2048
#define BATCH 4
#define MTOT  (BATCH*SEQ)

typedef __attribute__((ext_vector_type(8)))  short short8;
typedef __attribute__((ext_vector_type(4)))  float f32x4;
typedef __attribute__((ext_vector_type(16))) float f32x16;

#define GLOAD_LDS16(g, l) \
  __builtin_amdgcn_global_load_lds((const __attribute__((address_space(1))) void*)(g), \
                                   (__attribute__((address_space(3))) void*)(l), 16, 0, 0)

__device__ inline unsigned short f2bf(float f) {
  union { float f; unsigned u; } v; v.f = f;
  unsigned r = v.u + 0x7FFF + ((v.u >> 16) & 1);
  return (unsigned short)(r >> 16);
}

__device__ inline unsigned cvtpk(float lo, float hi) {
  unsigned r;
  asm("v_cvt_pk_bf16_f32 %0, %1, %2" : "=v"(r) : "v"(lo), "v"(hi));
  return r;
}

// raw 2^x — single trans-pipe instr; inputs bounded (|x| < ~8), no edge cases
__device__ inline float vexp2(float x) {
  float r;
  asm("v_exp_f32 %0, %1" : "=v"(r) : "v"(x));
  return r;
}

// v_permlane32_swap_b32 vdst, vsrc — HW semantics (R6/R7 falsification test):
// new vdst[32:63] = old vsrc[0:31]; new vsrc[0:31] = old vdst[32:63].
#define PLSWAP(a, b) asm("v_permlane32_swap_b32 %0, %1" : "+v"(a), "+v"(b))

__device__ inline short8 mk8(unsigned w0, unsigned w1, unsigned w2, unsigned w3) {
  union { unsigned u[4]; short8 s; } x;
  x.u[0] = w0; x.u[1] = w1; x.u[2] = w2; x.u[3] = w3;
  return x.s;
}

// ---------- kernel 1: x fp32 -> bf16 ----------
__global__ void cvt_x(const float* __restrict__ x, unsigned short* __restrict__ xb) {
  int i = (blockIdx.x * blockDim.x + threadIdx.x) * 8;
  f32x4 a = *(const f32x4*)(x + i);
  f32x4 b = *(const f32x4*)(x + i + 4);
  unsigned short o[8];
  o[0]=f2bf(a[0]); o[1]=f2bf(a[1]); o[2]=f2bf(a[2]); o[3]=f2bf(a[3]);
  o[4]=f2bf(b[0]); o[5]=f2bf(b[1]); o[6]=f2bf(b[2]); o[7]=f2bf(b[3]);
  *(short8*)(xb + i) = *(short8*)o;
}

// ---------- kernel 2: W [K][N] fp32 -> Wt [N][K] bf16 (x3) ----------
__global__ void transpose_w(const float* __restrict__ Wq, const float* __restrict__ Wk,
                            const float* __restrict__ Wv, unsigned short* __restrict__ Wtb) {
  __shared__ float tile[32][33];
  int wsel = blockIdx.z;
  const float* W = wsel == 0 ? Wq : (wsel == 1 ? Wk : Wv);
  int k0 = blockIdx.x * 32, n0 = blockIdx.y * 32;
  int tx = threadIdx.x & 31, ty = threadIdx.x >> 5;
  for (int i = 0; i < 4; ++i)
    tile[ty + i*8][tx] = W[(k0 + ty + i*8) * EMBED + n0 + tx];
  __syncthreads();
  unsigned short* o = Wtb + wsel * EMBED * EMBED;
  for (int i = 0; i < 4; ++i)
    o[(n0 + ty + i*8) * EMBED + k0 + tx] = f2bf(tile[tx][ty + i*8]);
}

// ---------- kernel 3: QKV projection GEMM ----------
// Q output is pre-scaled by 0.125*log2(e) so attn's softmax needs no per-score FMA.
__global__ __launch_bounds__(256)
void qkv_gemm(const unsigned short* __restrict__ xb, const unsigned short* __restrict__ Wtb,
              const float* __restrict__ bq, const float* __restrict__ bk, const float* __restrict__ bv,
              unsigned short* __restrict__ Qb, unsigned short* __restrict__ Kb,
              unsigned short* __restrict__ Vt) {
  __shared__ unsigned short As[128 * 72];
  __shared__ unsigned short Bs[128 * 72];
  int wsel = blockIdx.z;
  int m0 = blockIdx.x * 128, n0 = blockIdx.y * 128;
  int t = threadIdx.x, lane = t & 63, wave = t >> 6;
  int wr = wave >> 1, wc = wave & 1;
  int lr = lane & 15, lg = lane >> 4;
  const unsigned short* Wt = Wtb + wsel * (EMBED * EMBED);
  const float* bias = wsel == 0 ? bq : (wsel == 1 ? bk : bv);

  f32x4 acc[4][4] = {};

  for (int kt = 0; kt < EMBED / 64; ++kt) {
    int k0 = kt * 64;
    for (int i = 0; i < 4; ++i) {
      int c = i * 256 + t;
      int row = c >> 3, col8 = c & 7;
      short8 va = *(const short8*)(xb + (m0 + row) * EMBED + k0 + col8 * 8);
      short8 vb = *(const short8*)(Wt + (n0 + row) * EMBED + k0 + col8 * 8);
      *(short8*)(As + row * 72 + col8 * 8) = va;
      *(short8*)(Bs + row * 72 + col8 * 8) = vb;
    }
    __syncthreads();
    for (int kk = 0; kk < 2; ++kk) {
      short8 af[4], bfr[4];
      for (int mf = 0; mf < 4; ++mf)
        af[mf] = *(const short8*)(As + (wr * 64 + mf * 16 + lr) * 72 + kk * 32 + lg * 8);
      for (int nf = 0; nf < 4; ++nf)
        bfr[nf] = *(const short8*)(Bs + (wc * 64 + nf * 16 + lr) * 72 + kk * 32 + lg * 8);
      for (int mf = 0; mf < 4; ++mf)
        for (int nf = 0; nf < 4; ++nf)
          acc[mf][nf] = __builtin_amdgcn_mfma_f32_16x16x32_bf16(af[mf], bfr[nf], acc[mf][nf], 0, 0, 0);
    }
    __syncthreads();
  }

  const float SCLQ = 0.125f * 1.44269504088896340736f;
  for (int nf = 0; nf < 4; ++nf) {
    int n = n0 + wc * 64 + nf * 16 + lr;
    float bval = bias[n];
    int h = n >> 6, d = n & 63;
    for (int mf = 0; mf < 4; ++mf) {
      for (int r = 0; r < 4; ++r) {
        int m = m0 + wr * 64 + mf * 16 + lg * 4 + r;
        int b = m >> 11, s = m & 2047;
        float oval = acc[mf][nf][r] + bval;
        if (wsel == 0) oval *= SCLQ;   // wave-uniform branch
        unsigned short bfv = f2bf(oval);
        if (wsel == 0)      Qb[((b * HEADS + h) * SEQ + s) * HDIM + d] = bfv;
        else if (wsel == 1) Kb[((b * HEADS + h) * SEQ + s) * HDIM + d] = bfv;
        else                Vt[((b * HEADS + h) * HDIM + d) * SEQ + s] = bfv;
      }
    }
  }
}

// ---------- kernel 4: flash attention, 32x32 MFMA, swapped QK^T ----------
// T1: XCD-aware block swizzle — each XCD owns 8 contiguous bh (4 MB K/V = its L2),
// so staging loads are L2 hits instead of cross-XCD HBM misses (FETCH 139->~60MB).
// T5: setprio(1) around MFMA clusters. T3/T4 triple-buffer + counted vmcnt kept.
__global__ __launch_bounds__(256)
void attn(const unsigned short* __restrict__ Qb, const unsigned short* __restrict__ Kb,
          const unsigned short* __restrict__ Vt, const float* __restrict__ rel_bias,
          float* __restrict__ out) {
  __shared__ unsigned short KVs[24576];   // K0|K1|K2 | V0|V1|V2, 8 KB per tile
  __shared__ float bias_l[33];
  __shared__ float dld[4][32];
  // T1 swizzle: XCD = bid%8 gets logical blocks [ (bid%8)*128, +128 ) => 8 bh/XCD
  int lid = ((blockIdx.x & 7) << 7) + (blockIdx.x >> 3);
  int bh = lid >> 4;
  int qb = lid & 15;
  int b = bh >> 4, h = bh & 15;
  int t = threadIdx.x, lane = t & 63, wave = t >> 6;
  int l31 = lane & 31, hi = lane >> 5;
  const float LOG2E = 1.44269504088896340736f;
  if (t < 33) bias_l[t] = rel_bias[t * HEADS + h] * LOG2E;

  int qw0 = qb * 128 + wave * 32;                  // this wave's 32 q-rows
  const unsigned short* Qp = Qb + (bh * SEQ + qw0) * HDIM;
  const unsigned short* Kp = Kb + bh * SEQ * HDIM;
  const unsigned short* Vp = Vt + bh * HDIM * SEQ;

  // Q as B-operand fragments: col=q=l31, k(d) = ks*16 + hi*8 + j
  short8 qf[4];
  #pragma unroll
  for (int ks = 0; ks < 4; ++ks)
    qf[ks] = *(const short8*)(Qp + l31 * HDIM + ks * 16 + hi * 8);

  // precomputed per-lane LDS byte offsets, shared by K and V reads:
  // row = rs*32+l31, slot = (ks*2+hi)^(row&7);  off = row*128 + slot*16
  unsigned rbo[2][4];
  #pragma unroll
  for (int rs = 0; rs < 2; ++rs)
    #pragma unroll
    for (int ks = 0; ks < 4; ++ks) {
      int row = rs * 32 + l31;
      rbo[rs][ks] = (unsigned)((row << 7) + ((((ks << 1) | hi) ^ (row & 7)) << 4));
    }
  // byte layout: K buf i at i*8192; V buf i at 24576 + i*8192
  #define LDK(rs, ks, BUF) \
    (*(const short8*)((const char*)KVs + rbo[rs][ks] + (BUF) * 8192))
  #define LDVv(rs, ks, BUF) \
    (*(const short8*)((const char*)KVs + rbo[rs][ks] + 24576 + (BUF) * 8192))

  f32x16 O0 = {}, O1 = {};
  float ls0 = 0.f, ls1 = 0.f;
  int q = qw0 + l31;

  // staging: wave stages rows [wave*16, wave*16+16)
  int srow0 = (wave << 4) + (lane >> 3);
  int sslot = lane & 7;

  #define STAGE(BUF, key0_)                                                          \
    for (int j = 0; j < 2; ++j) {                                                    \
      int srow = srow0 + j * 8;                                                      \
      int cs = sslot ^ (srow & 7);                                                   \
      GLOAD_LDS16(Kp + ((key0_) + srow) * HDIM + cs * 8,                             \
                  (char*)KVs + (BUF) * 8192 + ((((wave << 4) + j * 8) << 6) << 1));  \
      GLOAD_LDS16(Vp + srow * SEQ + (key0_) + cs * 8,                                \
                  (char*)KVs + 24576 + (BUF) * 8192 + ((((wave << 4) + j * 8) << 6) << 1)); \
    }

  #define WAITV4 asm volatile("s_waitcnt vmcnt(4)" ::: "memory");
  #define WAITV0 asm volatile("s_waitcnt vmcnt(0)" ::: "memory");
  #define BAR    __builtin_amdgcn_s_barrier();

  float cbLo, cbHi;

  // softmax + pack + PV for one 32-key block held in acc SACC
  #define PROC(SACC, KOFF, BUF)  {                                                   \
    float pv[16];                                                                    \
    int kbase = key0 + (KOFF);                                                       \
    if (kbase >= qw0 + 47) {                                                         \
      _Pragma("unroll") for (int r = 0; r < 16; ++r)                                 \
        pv[r] = vexp2(SACC[r] + cbHi);                                               \
    } else if (kbase <= qw0 - 47) {                                                  \
      _Pragma("unroll") for (int r = 0; r < 16; ++r)                                 \
        pv[r] = vexp2(SACC[r] + cbLo);                                               \
    } else {                                                                         \
      _Pragma("unroll") for (int r = 0; r < 16; ++r) {                               \
        int key = kbase + (r & 3) + 8 * (r >> 2) + 4 * hi;                           \
        int rel = key - q;                                                           \
        rel = rel < -16 ? -16 : (rel > 16 ? 16 : rel);                               \
        pv[r] = vexp2(SACC[r] + bias_l[rel + 16]);                                   \
      }                                                                              \
    }                                                                                \
    ls0 += ((pv[0] + pv[1]) + (pv[2] + pv[3])) + ((pv[4] + pv[5]) + (pv[6] + pv[7]));\
    ls1 += ((pv[8] + pv[9]) + (pv[10] + pv[11])) + ((pv[12] + pv[13]) + (pv[14] + pv[15]));\
    unsigned a0 = cvtpk(pv[0], pv[1]),  a1 = cvtpk(pv[4], pv[5]);   PLSWAP(a0, a1);  \
    unsigned a2 = cvtpk(pv[2], pv[3]),  a3 = cvtpk(pv[6], pv[7]);   PLSWAP(a2, a3);  \
    unsigned b0 = cvtpk(pv[8], pv[9]),  b1 = cvtpk(pv[12], pv[13]); PLSWAP(b0, b1);  \
    unsigned b2 = cvtpk(pv[10], pv[11]), b3 = cvtpk(pv[14], pv[15]); PLSWAP(b2, b3); \
    short8 pa0 = mk8(a0, a2, a1, a3);                                                \
    short8 pa1 = mk8(b0, b2, b1, b3);                                                \
    __builtin_amdgcn_s_setprio(1);                                                   \
    O0 = __builtin_amdgcn_mfma_f32_32x32x16_bf16(pa0, LDVv(0, (KOFF)/16, BUF),     O0, 0, 0, 0); \
    O1 = __builtin_amdgcn_mfma_f32_32x32x16_bf16(pa0, LDVv(1, (KOFF)/16, BUF),     O1, 0, 0, 0); \
    O0 = __builtin_amdgcn_mfma_f32_32x32x16_bf16(pa1, LDVv(0, (KOFF)/16 + 1, BUF), O0, 0, 0, 0); \
    O1 = __builtin_amdgcn_mfma_f32_32x32x16_bf16(pa1, LDVv(1, (KOFF)/16 + 1, BUF), O1, 0, 0, 0); \
    __builtin_amdgcn_s_setprio(0);                                                   \
  }

  // One 32-key half: QK^T chain then its softmax+PV, as a closed region.
  #define HALF(RS, KOFF, BUF)  {                                                     \
    f32x16 s_ = {};                                                                  \
    __builtin_amdgcn_s_setprio(1);                                                   \
    _Pragma("unroll") for (int ks = 0; ks < 4; ++ks)                                 \
      s_ = __builtin_amdgcn_mfma_f32_32x32x16_bf16(LDK(RS, ks, BUF), qf[ks], s_, 0, 0, 0); \
    __builtin_amdgcn_s_setprio(0);                                                   \
    PROC(s_, KOFF, BUF)                                                              \
  }

  #define COMPUTE(BUF, KEY0)  {                                                      \
    int key0 = (KEY0);                                                               \
    HALF(0, 0, BUF)                                                                  \
    HALF(1, 32, BUF)                                                                 \
  }

  // prologue: stage tiles 0,1; wait tile 0; barrier (also covers bias_l)
  STAGE(0, 0)
  STAGE(1, 64)
  WAITV4
  __syncthreads();
  cbLo = bias_l[0]; cbHi = bias_l[32];

  // main: 30 phases in 10 x3-unrolled iterations; tile kb+2 staged each phase
  for (int i = 0; i < 10; ++i) {
    int t3 = i * 3;
    STAGE(2, (t3 + 2) * 64)  COMPUTE(0, t3 * 64)        WAITV4 BAR
    STAGE(0, (t3 + 3) * 64)  COMPUTE(1, (t3 + 1) * 64)  WAITV4 BAR
    STAGE(1, (t3 + 4) * 64)  COMPUTE(2, (t3 + 2) * 64)  WAITV4 BAR
  }
  // tail: tiles 30, 31 (no more staging; drain)
  COMPUTE(0, 30 * 64)
  WAITV0 BAR
  COMPUTE(1, 31 * 64)

  // ---- epilogue: denom per q, normalize, store ----
  float lsum = ls0 + ls1;
  float denom = lsum + __shfl_xor(lsum, 32, 64);
  if (lane < 32) dld[wave][l31] = 1.0f / denom;   // wave-local, wave-synchronous
  float* op = out + (b * SEQ + qw0) * EMBED + h * HDIM;
  #pragma unroll
  for (int r = 0; r < 16; ++r) {
    int ql = (r & 3) + 8 * (r >> 2) + 4 * hi;
    float inv = dld[wave][ql];
    op[ql * EMBED + l31]      = O0[r] * inv;
    op[ql * EMBED + 32 + l31] = O1[r] * inv;
  }
  #undef STAGE
  #undef LDK
  #undef LDVv
  #undef PROC
  #undef HALF
  #undef COMPUTE
}

extern "C" void kernel_launch(void* const* d_in, const int* in_sizes, int n_in,
                              void* d_out, int out_size, void* d_ws, size_t ws_size,
                              hipStream_t stream) {
  const float* x        = (const float*)d_in[0];
  const float* Wq       = (const float*)d_in[1];
  const float* bq       = (const float*)d_in[2];
  const float* Wk       = (const float*)d_in[3];
  const float* bk       = (const float*)d_in[4];
  const float* Wv       = (const float*)d_in[5];
  const float* bv       = (const float*)d_in[6];
  const float* rel_bias = (const float*)d_in[7];
  float* out = (float*)d_out;

  char* ws = (char*)d_ws;
  unsigned short* xb  = (unsigned short*)(ws);                 // 16 MB
  unsigned short* Wtb = (unsigned short*)(ws + 16777216);      // 6 MB
  unsigned short* Qb  = (unsigned short*)(ws + 23068672);      // 16 MB
  unsigned short* Kb  = (unsigned short*)(ws + 39845888);      // 16 MB
  unsigned short* Vt  = (unsigned short*)(ws + 56623104);      // 16 MB (total 70 MB)

  cvt_x<<<MTOT * EMBED / (256 * 8), 256, 0, stream>>>(x, xb);
  transpose_w<<<dim3(32, 32, 3), 256, 0, stream>>>(Wq, Wk, Wv, Wtb);
  qkv_gemm<<<dim3(MTOT / 128, EMBED / 128, 3), 256, 0, stream>>>(xb, Wtb, bq, bk, bv, Qb, Kb, Vt);
  attn<<<dim3(SEQ / 128 * BATCH * HEADS), 256, 0, stream>>>(Qb, Kb, Vt, rel_bias, out);
}